// Round 4
// baseline (5167.870 us; speedup 1.0000x reference)
//
#include <hip/hip_runtime.h>
#include <hip/hip_fp16.h>

#define NUM_USERS 100000
#define NUM_ITEMS 50000
#define NTOT (NUM_USERS + NUM_ITEMS)
#define EMBED_DIM 64
#define NNZ_E 4800000
#define NUM_LAYERS 3

#define RPB 64                                   // rows per bucket
#define NBUCK ((NTOT + RPB - 1) / RPB)           // 2344
#define BCAP 2432                                // mean 2048 + ~8.5 sigma
#define EDGES_PER_BLOCK 8192
#define DMASK 0x3FFFF                            // 18 bits for dst (<150000<2^18)

// ---- init: cur(fp16) = concat(user,item); out(fp32 acc) = same ----
__global__ void __launch_bounds__(256)
k_init(const float* __restrict__ ue, const float* __restrict__ ie,
       __half* __restrict__ cur, float* __restrict__ out) {
    const long long total2 = (long long)NTOT * EMBED_DIM / 2;
    const long long u2 = (long long)NUM_USERS * EMBED_DIM / 2;
    const float2* ue2 = (const float2*)ue;
    const float2* ie2 = (const float2*)ie;
    float2* out2 = (float2*)out;
    __half2* cur2 = (__half2*)cur;
    for (long long i = (long long)blockIdx.x * blockDim.x + threadIdx.x;
         i < total2; i += (long long)gridDim.x * blockDim.x) {
        float2 v = (i < u2) ? ue2[i] : ie2[i - u2];
        out2[i] = v;
        cur2[i] = __floats2half2_rn(v.x, v.y);
    }
}

// ---- phase 1: coarse 64-row bucket scatter (block-aggregated) ----
__global__ void __launch_bounds__(256)
k_bucket(const int* __restrict__ src, const int* __restrict__ dst,
         const float* __restrict__ val, int* __restrict__ cursor,
         int2* __restrict__ outA) {
    __shared__ int h[NBUCK];
    __shared__ int base[NBUCK];
    for (int i = threadIdx.x; i < NBUCK; i += 256) h[i] = 0;
    __syncthreads();
    long long e0 = (long long)blockIdx.x * EDGES_PER_BLOCK;
    int n = (int)(((long long)NNZ_E - e0) < EDGES_PER_BLOCK ? (NNZ_E - e0)
                                                            : EDGES_PER_BLOCK);
    for (int i = threadIdx.x; i < n; i += 256)
        atomicAdd(&h[src[e0 + i] >> 6], 1);
    __syncthreads();
    for (int i = threadIdx.x; i < NBUCK; i += 256) {
        int c = h[i];
        base[i] = (c > 0) ? atomicAdd(&cursor[i], c) : 0;
        h[i] = 0;
    }
    __syncthreads();
    for (int i = threadIdx.x; i < n; i += 256) {
        int s = src[e0 + i];
        int d = dst[e0 + i];
        float v = val[e0 + i];
        int b = s >> 6;
        int off = base[b] + atomicAdd(&h[b], 1);
        outA[(long long)b * BCAP + off] =
            make_int2(d | ((s & 63) << 18), __float_as_int(v));
    }
}

// ---- SpMM: one block per 64-row bucket, edge-parallel, LDS fp32 accum ----
__global__ void __launch_bounds__(256, 4)
k_spmm_lds(const int2* __restrict__ edges, const int* __restrict__ cnt,
           const __half* __restrict__ x, __half* __restrict__ nxt,
           float* __restrict__ out, float scale) {
    __shared__ float acc[RPB * EMBED_DIM];   // 16 KB
    int b = blockIdx.x;
    int t = threadIdx.x;
    for (int i = t; i < RPB * EMBED_DIM; i += 256) acc[i] = 0.f;
    __syncthreads();

    int n = cnt[b];
    const int2* e = edges + (long long)b * BCAP;
    int lane = t & 63;
    int wid = t >> 6;

    int nFull = n & ~31;                      // 4 waves x 8-edge chunks
    for (int j = wid * 8; j < nFull; j += 32) {
        int2 ee[8];
#pragma unroll
        for (int k = 0; k < 8; ++k) ee[k] = e[j + k];
        float xv[8];
#pragma unroll
        for (int k = 0; k < 8; ++k)
            xv[k] = __half2float(x[(long long)(ee[k].x & DMASK) * EMBED_DIM + lane]);
#pragma unroll
        for (int k = 0; k < 8; ++k) {
            int r = (ee[k].x >> 18) & 63;
            atomicAdd(&acc[r * EMBED_DIM + lane], __int_as_float(ee[k].y) * xv[k]);
        }
    }
    for (int j = nFull + wid; j < n; j += 4) {
        int2 ee = e[j];
        float xv = __half2float(x[(long long)(ee.x & DMASK) * EMBED_DIM + lane]);
        int r = (ee.x >> 18) & 63;
        atomicAdd(&acc[r * EMBED_DIM + lane], __int_as_float(ee.y) * xv);
    }
    __syncthreads();

    // flush: 64 rows -> fp16 nxt + fused fp32 out accumulate
    int row0 = b * RPB;
    for (int i = t; i < RPB * EMBED_DIM / 2; i += 256) {
        int r = i >> 5;
        int c2 = (i & 31) * 2;
        int row = row0 + r;
        if (row >= NTOT) continue;
        float a0 = acc[r * EMBED_DIM + c2];
        float a1 = acc[r * EMBED_DIM + c2 + 1];
        long long o = (long long)row * EMBED_DIM + c2;
        *(__half2*)(nxt + o) = __floats2half2_rn(a0, a1);
        float2 ov = *(float2*)(out + o);
        ov.x = (ov.x + a0) * scale;
        ov.y = (ov.y + a1) * scale;
        *(float2*)(out + o) = ov;
    }
}

extern "C" void kernel_launch(void* const* d_in, const int* in_sizes, int n_in,
                              void* d_out, int out_size, void* d_ws, size_t ws_size,
                              hipStream_t stream) {
    const float* user_emb = (const float*)d_in[0];
    const float* item_emb = (const float*)d_in[1];
    const int* edge_src   = (const int*)d_in[2];
    const int* edge_dst   = (const int*)d_in[3];
    const float* edge_val = (const float*)d_in[4];
    float* out = (float*)d_out;

    // ---- workspace ----
    char* p = (char*)d_ws;
    const size_t halfMat = (size_t)NTOT * EMBED_DIM * sizeof(__half);   // 19.2 MB
    const size_t buckBytes = (size_t)NBUCK * BCAP * sizeof(int2);       // 45.6 MB
    __half* bufA = (__half*)p;               p += halfMat;
    __half* bufB = (__half*)p;               p += halfMat;
    int2* bucketed = (int2*)p;               p += buckBytes;
    int* cursor = (int*)p;                   p += (size_t)NBUCK * sizeof(int);

    // 1. bucket the edges (cursor ends up = per-bucket count)
    hipMemsetAsync(cursor, 0, (size_t)NBUCK * sizeof(int), stream);
    const int bucketBlocks = (NNZ_E + EDGES_PER_BLOCK - 1) / EDGES_PER_BLOCK;  // 586
    hipLaunchKernelGGL(k_bucket, dim3(bucketBlocks), dim3(256), 0, stream,
                       edge_src, edge_dst, edge_val, cursor, bucketed);

    // 2. init cur (fp16) + out accumulator (fp32)
    hipLaunchKernelGGL(k_init, dim3(2048), dim3(256), 0, stream,
                       user_emb, item_emb, bufA, out);

    // 3. three edge-parallel SpMM layers with fused accumulation
    __half* cur = bufA;
    __half* nxt = bufB;
    for (int layer = 0; layer < NUM_LAYERS; ++layer) {
        float scale = (layer == NUM_LAYERS - 1) ? (1.0f / (NUM_LAYERS + 1)) : 1.0f;
        hipLaunchKernelGGL(k_spmm_lds, dim3(NBUCK), dim3(256), 0, stream,
                           bucketed, cursor, cur, nxt, out, scale);
        __half* tmp = cur; cur = nxt; nxt = tmp;
    }
}

// Round 5
// 589.913 us; speedup vs baseline: 8.7604x; 8.7604x over previous
//
#include <hip/hip_runtime.h>
#include <hip/hip_fp16.h>

#define NUM_USERS 100000
#define NUM_ITEMS 50000
#define NTOT (NUM_USERS + NUM_ITEMS)
#define EMBED_DIM 64
#define NNZ_E 4800000
#define NUM_LAYERS 3

#define ROWS_PER_BUCKET 256
#define NBUCK ((NTOT + ROWS_PER_BUCKET - 1) / ROWS_PER_BUCKET)   // 586
#define BCAP 8960                   // mean 8191 + 8.5 sigma
#define EDGES_PER_BLOCK 8192
#define DMASK 0x3FFFF               // 18 bits for dst (< 150000 < 2^18)

// ---------------- init: b0(fp16) = concat(user_emb, item_emb) ----------------
__global__ void __launch_bounds__(256)
k_init(const float* __restrict__ ue, const float* __restrict__ ie,
       __half* __restrict__ b0) {
    const long long total2 = (long long)NTOT * EMBED_DIM / 2;
    const long long u2 = (long long)NUM_USERS * EMBED_DIM / 2;
    const float2* ue2 = (const float2*)ue;
    const float2* ie2 = (const float2*)ie;
    __half2* b02 = (__half2*)b0;
    for (long long i = (long long)blockIdx.x * blockDim.x + threadIdx.x;
         i < total2; i += (long long)gridDim.x * blockDim.x) {
        float2 v = (i < u2) ? ue2[i] : ie2[i - u2];
        b02[i] = __floats2half2_rn(v.x, v.y);
    }
}

// ---------------- phase 1: coarse bucket scatter (block-aggregated) ----------
__global__ void __launch_bounds__(256)
k_bucket(const int* __restrict__ src, const int* __restrict__ dst,
         const float* __restrict__ val, int* __restrict__ cursor,
         int2* __restrict__ outA) {
    __shared__ int h[NBUCK];
    __shared__ int base[NBUCK];
    for (int i = threadIdx.x; i < NBUCK; i += 256) h[i] = 0;
    __syncthreads();
    long long e0 = (long long)blockIdx.x * EDGES_PER_BLOCK;
    int n = (int)(((long long)NNZ_E - e0) < EDGES_PER_BLOCK ? (NNZ_E - e0)
                                                            : EDGES_PER_BLOCK);
    for (int i = threadIdx.x; i < n; i += 256)
        atomicAdd(&h[src[e0 + i] >> 8], 1);
    __syncthreads();
    for (int i = threadIdx.x; i < NBUCK; i += 256) {
        int c = h[i];
        base[i] = (c > 0) ? atomicAdd(&cursor[i], c) : 0;
        h[i] = 0;
    }
    __syncthreads();
    for (int i = threadIdx.x; i < n; i += 256) {
        int s = src[e0 + i];
        int d = dst[e0 + i];
        float v = val[e0 + i];
        int b = s >> 8;
        int off = base[b] + atomicAdd(&h[b], 1);
        outA[(long long)b * BCAP + off] =
            make_int2(d | ((s & 255) << 18), __float_as_int(v));
    }
}

// ---------------- phase 2: per-bucket LDS counting sort -> row-grouped ------
__global__ void __launch_bounds__(256)
k_sortbucket(const int2* __restrict__ inAll, const int* __restrict__ cursor,
             int2* __restrict__ outB, int2* __restrict__ rp) {
    __shared__ int h[ROWS_PER_BUCKET];
    __shared__ int excl[ROWS_PER_BUCKET];
    __shared__ int cur[ROWS_PER_BUCKET];
    int b = blockIdx.x;
    int t = threadIdx.x;
    int cnt = cursor[b];
    const int2* in = inAll + (long long)b * BCAP;
    h[t] = 0;
    __syncthreads();
    for (int i = t; i < cnt; i += 256)
        atomicAdd(&h[(in[i].x >> 18) & 255], 1);
    __syncthreads();
    int v = h[t];
    excl[t] = v;
    __syncthreads();
    for (int off = 1; off < 256; off <<= 1) {
        int x = (t >= off) ? excl[t - off] : 0;
        __syncthreads();
        excl[t] += x;
        __syncthreads();
    }
    int myExcl = excl[t] - v;
    cur[t] = myExcl;
    long long gb = (long long)b * BCAP;
    int row = b * ROWS_PER_BUCKET + t;
    if (row < NTOT) rp[row] = make_int2((int)(gb + myExcl), (int)(gb + myExcl + v));
    __syncthreads();
    for (int i = t; i < cnt; i += 256) {
        int2 e = in[i];
        int r = (e.x >> 18) & 255;
        int slot = atomicAdd(&cur[r], 1);
        outB[gb + slot] = e;
    }
}

// ---------------- CSR SpMM: one wave per row, fp16 gather, fp32 acc ---------
__global__ void __launch_bounds__(256)
k_spmm_csr(const int2* __restrict__ edges, const int2* __restrict__ rp,
           const __half* __restrict__ x, __half* __restrict__ nxt) {
    int row = blockIdx.x * 4 + (threadIdx.x >> 6);
    int lane = threadIdx.x & 63;
    if (row >= NTOT) return;
    int2 be = rp[row];
    int beg = be.x;
    int end = be.y;
    float acc = 0.f;
    int j = beg;
    for (; j + 8 <= end; j += 8) {
        int2 e[8];
        float xv[8];
#pragma unroll
        for (int k = 0; k < 8; ++k) e[k] = edges[j + k];
#pragma unroll
        for (int k = 0; k < 8; ++k)
            xv[k] = __half2float(x[(long long)(e[k].x & DMASK) * EMBED_DIM + lane]);
#pragma unroll
        for (int k = 0; k < 8; ++k) acc = fmaf(__int_as_float(e[k].y), xv[k], acc);
    }
    for (; j < end; ++j) {
        int2 e = edges[j];
        acc = fmaf(__int_as_float(e.y),
                   __half2float(x[(long long)(e.x & DMASK) * EMBED_DIM + lane]), acc);
    }
    nxt[(long long)row * EMBED_DIM + lane] = __float2half(acc);
}

// ---------------- final: out = (ego0 + b1 + b2 + b3) / 4 --------------------
__global__ void __launch_bounds__(256)
k_final(const float* __restrict__ ue, const float* __restrict__ ie,
        const __half* __restrict__ b1, const __half* __restrict__ b2,
        const __half* __restrict__ b3, float* __restrict__ out) {
    const long long total2 = (long long)NTOT * EMBED_DIM / 2;
    const long long u2 = (long long)NUM_USERS * EMBED_DIM / 2;
    const float2* ue2 = (const float2*)ue;
    const float2* ie2 = (const float2*)ie;
    const __half2* b12 = (const __half2*)b1;
    const __half2* b22 = (const __half2*)b2;
    const __half2* b32 = (const __half2*)b3;
    float2* out2 = (float2*)out;
    const float s = 1.0f / (NUM_LAYERS + 1);
    for (long long i = (long long)blockIdx.x * blockDim.x + threadIdx.x;
         i < total2; i += (long long)gridDim.x * blockDim.x) {
        float2 v = (i < u2) ? ue2[i] : ie2[i - u2];
        float2 a = __half22float2(b12[i]);
        float2 b = __half22float2(b22[i]);
        float2 c = __half22float2(b32[i]);
        float2 r;
        r.x = (v.x + a.x + b.x + c.x) * s;
        r.y = (v.y + a.y + b.y + c.y) * s;
        out2[i] = r;
    }
}

extern "C" void kernel_launch(void* const* d_in, const int* in_sizes, int n_in,
                              void* d_out, int out_size, void* d_ws, size_t ws_size,
                              hipStream_t stream) {
    const float* user_emb = (const float*)d_in[0];
    const float* item_emb = (const float*)d_in[1];
    const int* edge_src   = (const int*)d_in[2];
    const int* edge_dst   = (const int*)d_in[3];
    const float* edge_val = (const float*)d_in[4];
    float* out = (float*)d_out;

    // ---- workspace layout ----
    // [0 .. 76.8MB) : b0..b3 (4 x 19.2MB fp16).  bucketedA (42MB) ALIASES this
    //                 region; it is dead before k_init writes b0.
    // then bucketedB (42MB, live all layers), rp (int2), cursor.
    char* p = (char*)d_ws;
    const size_t halfMat = (size_t)NTOT * EMBED_DIM * sizeof(__half);   // 19.2 MB
    const size_t buckBytes = (size_t)NBUCK * BCAP * sizeof(int2);       // 42.0 MB
    __half* b0 = (__half*)p;                 p += halfMat;
    __half* b1 = (__half*)p;                 p += halfMat;
    __half* b2 = (__half*)p;                 p += halfMat;
    __half* b3 = (__half*)p;                 p += halfMat;
    int2* bucketedA = (int2*)d_ws;           // alias of b0..b3 region
    int2* bucketedB = (int2*)p;              p += buckBytes;
    int2* rp = (int2*)p;                     p += ((size_t)NTOT + 8) * sizeof(int2);
    int* cursor = (int*)p;                   p += (size_t)NBUCK * sizeof(int);

    // 1. coarse bucket scatter
    hipMemsetAsync(cursor, 0, (size_t)NBUCK * sizeof(int), stream);
    const int bucketBlocks = (NNZ_E + EDGES_PER_BLOCK - 1) / EDGES_PER_BLOCK;  // 586
    hipLaunchKernelGGL(k_bucket, dim3(bucketBlocks), dim3(256), 0, stream,
                       edge_src, edge_dst, edge_val, cursor, bucketedA);

    // 2. per-bucket counting sort -> bucketedB + packed row ptrs
    hipLaunchKernelGGL(k_sortbucket, dim3(NBUCK), dim3(256), 0, stream,
                       bucketedA, cursor, bucketedB, rp);

    // 3. init b0 (fp16 ego), overwrites bucketedA region
    hipLaunchKernelGGL(k_init, dim3(2048), dim3(256), 0, stream,
                       user_emb, item_emb, b0);

    // 4. three gather-SpMM layers (write-only nxt)
    __half* bufs[4] = {b0, b1, b2, b3};
    const int spmmBlocks = (NTOT + 3) / 4;
    for (int layer = 0; layer < NUM_LAYERS; ++layer) {
        hipLaunchKernelGGL(k_spmm_csr, dim3(spmmBlocks), dim3(256), 0, stream,
                           bucketedB, rp, bufs[layer], bufs[layer + 1]);
    }

    // 5. out = (ego0 + b1 + b2 + b3) / 4
    hipLaunchKernelGGL(k_final, dim3(2048), dim3(256), 0, stream,
                       user_emb, item_emb, b1, b2, b3, out);
}

// Round 6
// 507.520 us; speedup vs baseline: 10.1826x; 1.1623x over previous
//
#include <hip/hip_runtime.h>
#include <hip/hip_fp16.h>

#define NUM_USERS 100000
#define NUM_ITEMS 50000
#define NTOT (NUM_USERS + NUM_ITEMS)
#define EMBED_DIM 64
#define NNZ_E 4800000
#define NUM_LAYERS 3

#define ROWS_PER_BUCKET 256
#define NBUCK ((NTOT + ROWS_PER_BUCKET - 1) / ROWS_PER_BUCKET)   // 586
#define BCAP 8960                   // mean 8191 + 8.5 sigma
#define EDGES_PER_BLOCK 16384
#define DMASK 0x3FFFF               // 18 bits for dst (< 150000 < 2^18)

// ---------------- init: b0(fp16) = concat(user_emb, item_emb) ----------------
__global__ void __launch_bounds__(256)
k_init(const float* __restrict__ ue, const float* __restrict__ ie,
       __half* __restrict__ b0) {
    const long long total2 = (long long)NTOT * EMBED_DIM / 2;
    const long long u2 = (long long)NUM_USERS * EMBED_DIM / 2;
    const float2* ue2 = (const float2*)ue;
    const float2* ie2 = (const float2*)ie;
    __half2* b02 = (__half2*)b0;
    for (long long i = (long long)blockIdx.x * blockDim.x + threadIdx.x;
         i < total2; i += (long long)gridDim.x * blockDim.x) {
        float2 v = (i < u2) ? ue2[i] : ie2[i - u2];
        b02[i] = __floats2half2_rn(v.x, v.y);
    }
}

// ---------------- phase 1: coarse bucket scatter (block-aggregated) ----------
__global__ void __launch_bounds__(256)
k_bucket(const int* __restrict__ src, const int* __restrict__ dst,
         const float* __restrict__ val, int* __restrict__ cursor,
         int2* __restrict__ outA) {
    __shared__ int h[NBUCK];
    __shared__ int base[NBUCK];
    for (int i = threadIdx.x; i < NBUCK; i += 256) h[i] = 0;
    __syncthreads();
    long long e0 = (long long)blockIdx.x * EDGES_PER_BLOCK;
    int n = (int)(((long long)NNZ_E - e0) < EDGES_PER_BLOCK ? (NNZ_E - e0)
                                                            : EDGES_PER_BLOCK);
    for (int i = threadIdx.x; i < n; i += 256)
        atomicAdd(&h[src[e0 + i] >> 8], 1);
    __syncthreads();
    for (int i = threadIdx.x; i < NBUCK; i += 256) {
        int c = h[i];
        base[i] = (c > 0) ? atomicAdd(&cursor[i], c) : 0;
        h[i] = 0;
    }
    __syncthreads();
    for (int i = threadIdx.x; i < n; i += 256) {
        int s = src[e0 + i];
        int d = dst[e0 + i];
        float v = val[e0 + i];
        int b = s >> 8;
        int off = base[b] + atomicAdd(&h[b], 1);
        outA[(long long)b * BCAP + off] =
            make_int2(d | ((s & 255) << 18), __float_as_int(v));
    }
}

// ---------------- phase 2: per-bucket LDS counting sort -> row-grouped ------
__global__ void __launch_bounds__(256)
k_sortbucket(const int2* __restrict__ inAll, const int* __restrict__ cursor,
             int2* __restrict__ outB, int2* __restrict__ rp) {
    __shared__ int h[ROWS_PER_BUCKET];
    __shared__ int excl[ROWS_PER_BUCKET];
    __shared__ int cur[ROWS_PER_BUCKET];
    int b = blockIdx.x;
    int t = threadIdx.x;
    int cnt = cursor[b];
    const int2* in = inAll + (long long)b * BCAP;
    h[t] = 0;
    __syncthreads();
    for (int i = t; i < cnt; i += 256)
        atomicAdd(&h[(in[i].x >> 18) & 255], 1);
    __syncthreads();
    int v = h[t];
    excl[t] = v;
    __syncthreads();
    for (int off = 1; off < 256; off <<= 1) {
        int x = (t >= off) ? excl[t - off] : 0;
        __syncthreads();
        excl[t] += x;
        __syncthreads();
    }
    int myExcl = excl[t] - v;
    cur[t] = myExcl;
    long long gb = (long long)b * BCAP;
    int row = b * ROWS_PER_BUCKET + t;
    if (row < NTOT) rp[row] = make_int2((int)(gb + myExcl), (int)(gb + myExcl + v));
    __syncthreads();
    for (int i = t; i < cnt; i += 256) {
        int2 e = in[i];
        int r = (e.x >> 18) & 255;
        int slot = atomicAdd(&cur[r], 1);
        outB[gb + slot] = e;
    }
}

// ---- CSR SpMM: one wave per row, half2 gather (32 lanes/row), 2 edges/instr --
// lanes 0-31 (sub=0) process even 8-edge groups, lanes 32-63 (sub=1) odd ones;
// each lane gathers a half2 (2 columns); halves combined by shfl_xor at the end.
__global__ void __launch_bounds__(256)
k_spmm_csr(const int2* __restrict__ edges, const int2* __restrict__ rp,
           const __half* __restrict__ x, __half* __restrict__ nxt) {
    int row = blockIdx.x * 4 + (threadIdx.x >> 6);
    int lane = threadIdx.x & 63;
    if (row >= NTOT) return;
    int2 be = rp[row];
    int beg = be.x;
    int end = be.y;
    int sub = lane >> 5;
    int l2 = lane & 31;
    const __half2* x2 = (const __half2*)x;   // row stride 32 half2
    float accx = 0.f, accy = 0.f;
    int j = beg;
    for (; j + 16 <= end; j += 16) {
        int2 e[8];
        __half2 xv[8];
#pragma unroll
        for (int k = 0; k < 8; ++k) e[k] = edges[j + sub * 8 + k];
#pragma unroll
        for (int k = 0; k < 8; ++k)
            xv[k] = x2[(long long)(e[k].x & DMASK) * 32 + l2];
#pragma unroll
        for (int k = 0; k < 8; ++k) {
            float w = __int_as_float(e[k].y);
            float2 xf = __half22float2(xv[k]);
            accx = fmaf(w, xf.x, accx);
            accy = fmaf(w, xf.y, accy);
        }
    }
    // tail (<16 edges): the two half-waves alternate edges
    for (int t2 = j + sub; t2 < end; t2 += 2) {
        int2 e = edges[t2];
        float w = __int_as_float(e.y);
        float2 xf = __half22float2(x2[(long long)(e.x & DMASK) * 32 + l2]);
        accx = fmaf(w, xf.x, accx);
        accy = fmaf(w, xf.y, accy);
    }
    // combine the two half-waves
    accx += __shfl_xor(accx, 32);
    accy += __shfl_xor(accy, 32);
    if (sub == 0)
        ((__half2*)nxt)[(long long)row * 32 + l2] = __floats2half2_rn(accx, accy);
}

// ---------------- final: out = (ego0 + b1 + b2 + b3) / 4 --------------------
__global__ void __launch_bounds__(256)
k_final(const float* __restrict__ ue, const float* __restrict__ ie,
        const __half* __restrict__ b1, const __half* __restrict__ b2,
        const __half* __restrict__ b3, float* __restrict__ out) {
    const long long total2 = (long long)NTOT * EMBED_DIM / 2;
    const long long u2 = (long long)NUM_USERS * EMBED_DIM / 2;
    const float2* ue2 = (const float2*)ue;
    const float2* ie2 = (const float2*)ie;
    const __half2* b12 = (const __half2*)b1;
    const __half2* b22 = (const __half2*)b2;
    const __half2* b32 = (const __half2*)b3;
    float2* out2 = (float2*)out;
    const float s = 1.0f / (NUM_LAYERS + 1);
    for (long long i = (long long)blockIdx.x * blockDim.x + threadIdx.x;
         i < total2; i += (long long)gridDim.x * blockDim.x) {
        float2 v = (i < u2) ? ue2[i] : ie2[i - u2];
        float2 a = __half22float2(b12[i]);
        float2 b = __half22float2(b22[i]);
        float2 c = __half22float2(b32[i]);
        float2 r;
        r.x = (v.x + a.x + b.x + c.x) * s;
        r.y = (v.y + a.y + b.y + c.y) * s;
        out2[i] = r;
    }
}

extern "C" void kernel_launch(void* const* d_in, const int* in_sizes, int n_in,
                              void* d_out, int out_size, void* d_ws, size_t ws_size,
                              hipStream_t stream) {
    const float* user_emb = (const float*)d_in[0];
    const float* item_emb = (const float*)d_in[1];
    const int* edge_src   = (const int*)d_in[2];
    const int* edge_dst   = (const int*)d_in[3];
    const float* edge_val = (const float*)d_in[4];
    float* out = (float*)d_out;

    // ---- workspace layout ----
    char* p = (char*)d_ws;
    const size_t halfMat = (size_t)NTOT * EMBED_DIM * sizeof(__half);   // 19.2 MB
    const size_t buckBytes = (size_t)NBUCK * BCAP * sizeof(int2);       // 42.0 MB
    __half* b0 = (__half*)p;                 p += halfMat;
    __half* b1 = (__half*)p;                 p += halfMat;
    __half* b2 = (__half*)p;                 p += halfMat;
    __half* b3 = (__half*)p;                 p += halfMat;
    int2* bucketedA = (int2*)d_ws;           // alias of b0..b3 region (dead before k_init)
    int2* bucketedB = (int2*)p;              p += buckBytes;
    int2* rp = (int2*)p;                     p += ((size_t)NTOT + 8) * sizeof(int2);
    int* cursor = (int*)p;                   p += (size_t)NBUCK * sizeof(int);

    // 1. coarse bucket scatter
    hipMemsetAsync(cursor, 0, (size_t)NBUCK * sizeof(int), stream);
    const int bucketBlocks = (NNZ_E + EDGES_PER_BLOCK - 1) / EDGES_PER_BLOCK;  // 293
    hipLaunchKernelGGL(k_bucket, dim3(bucketBlocks), dim3(256), 0, stream,
                       edge_src, edge_dst, edge_val, cursor, bucketedA);

    // 2. per-bucket counting sort -> bucketedB + packed row ptrs
    hipLaunchKernelGGL(k_sortbucket, dim3(NBUCK), dim3(256), 0, stream,
                       bucketedA, cursor, bucketedB, rp);

    // 3. init b0 (fp16 ego), overwrites bucketedA region
    hipLaunchKernelGGL(k_init, dim3(2048), dim3(256), 0, stream,
                       user_emb, item_emb, b0);

    // 4. three gather-SpMM layers (write-only nxt)
    __half* bufs[4] = {b0, b1, b2, b3};
    const int spmmBlocks = (NTOT + 3) / 4;
    for (int layer = 0; layer < NUM_LAYERS; ++layer) {
        hipLaunchKernelGGL(k_spmm_csr, dim3(spmmBlocks), dim3(256), 0, stream,
                           bucketedB, rp, bufs[layer], bufs[layer + 1]);
    }

    // 5. out = (ego0 + b1 + b2 + b3) / 4
    hipLaunchKernelGGL(k_final, dim3(2048), dim3(256), 0, stream,
                       user_emb, item_emb, b1, b2, b3, out);
}